// Round 2
// baseline (399.291 us; speedup 1.0000x reference)
//
#include <hip/hip_runtime.h>
#include <hip/hip_bf16.h>
#include <hip/hip_cooperative_groups.h>
#include <math.h>

namespace cg = cooperative_groups;

#define N_NODES 8192
#define DIM 256
#define WPR 256      // bitmap words per row = 8192/32
#define LSTRIDE 128  // adjacency list stride (ushort); max degree ~60 << 128

typedef __attribute__((ext_vector_type(8))) short bf16x8;
typedef __attribute__((ext_vector_type(4))) float f32x4;

// ================= phase bodies (shared by fused cooperative kernel and fallback) =================

__device__ __forceinline__ void phase_zero(unsigned* __restrict__ bitmap, int gtid, int nth) {
    const int NB4 = N_NODES * WPR / 4;  // 524288 uint4
    uint4 z = {0u, 0u, 0u, 0u};
    for (int i = gtid; i < NB4; i += nth) ((uint4*)bitmap)[i] = z;
}

__device__ __forceinline__ void phase_scatter(const int* __restrict__ rows, const int* __restrict__ cols,
                                              unsigned* __restrict__ bitmap, int E, int gtid, int nth) {
    for (int e = gtid; e < E; e += nth) {
        int r = rows[e];
        int c = cols[e];
        atomicOr(&bitmap[(size_t)r * WPR + (c >> 5)], 1u << (c & 31));
    }
}

__device__ __forceinline__ void phase_convert(const float* __restrict__ x, const float* __restrict__ W,
                                              __hip_bfloat16* __restrict__ xb, __hip_bfloat16* __restrict__ Wb,
                                              int gtid, int nth) {
    const int NX8 = N_NODES * DIM / 8;          // 262144
    const int NTOT = NX8 + DIM * DIM / 8;       // +8192
    for (int t = gtid; t < NTOT; t += nth) {
        const float* src = x;
        __hip_bfloat16* dst = xb;
        size_t off = (size_t)t * 8;
        if (t >= NX8) { src = W; dst = Wb; off = (size_t)(t - NX8) * 8; }
        float4 v0 = *(const float4*)(src + off);
        float4 v1 = *(const float4*)(src + off + 4);
        union { __hip_bfloat16 h[8]; uint4 u; } c;
        c.h[0] = __float2bfloat16(v0.x); c.h[1] = __float2bfloat16(v0.y);
        c.h[2] = __float2bfloat16(v0.z); c.h[3] = __float2bfloat16(v0.w);
        c.h[4] = __float2bfloat16(v1.x); c.h[5] = __float2bfloat16(v1.y);
        c.h[6] = __float2bfloat16(v1.z); c.h[7] = __float2bfloat16(v1.w);
        *(uint4*)(dst + off) = c.u;
    }
}

// g = bf16(x @ W^T), UNscaled (dinv_j applied in aggregate). 512 tiles of 64m x 64n.
__device__ __forceinline__ void phase_gemm(const short* __restrict__ xb, const short* __restrict__ Wb,
                                           __hip_bfloat16* __restrict__ g, int bid, int nblk, int tid) {
    int wave = tid >> 6, lane = tid & 63;
    int quad = lane >> 4, l16 = lane & 15;
    for (int t = bid; t < 512; t += nblk) {
        int bm = (t & 127) * 64 + wave * 16;
        int bn = (t >> 7) * 64;
        f32x4 acc[4] = {};
        const short* arow = xb + (size_t)(bm + l16) * DIM + quad * 8;
#pragma unroll
        for (int k0 = 0; k0 < DIM; k0 += 32) {
            bf16x8 a = *(const bf16x8*)(arow + k0);
#pragma unroll
            for (int s = 0; s < 4; s++) {
                bf16x8 b = *(const bf16x8*)(Wb + (size_t)(bn + s * 16 + l16) * DIM + k0 + quad * 8);
                acc[s] = __builtin_amdgcn_mfma_f32_16x16x32_bf16(a, b, acc[s], 0, 0, 0);
            }
        }
        // C/D layout: col = lane&15 (n), row = quad*4 + r (m)
#pragma unroll
        for (int r = 0; r < 4; r++) {
            int m = bm + quad * 4 + r;
#pragma unroll
            for (int s = 0; s < 4; s++)
                g[(size_t)m * DIM + bn + s * 16 + l16] = __float2bfloat16(acc[s][r]);
        }
    }
}

// one wave per row: popcount -> dinv, prefix-sum scatter of set bits -> compact list
__device__ __forceinline__ void phase_dinvlist(const unsigned* __restrict__ bitmap, float* __restrict__ dinv,
                                               int* __restrict__ lens, unsigned short* __restrict__ list,
                                               int bid, int nblk, int tid) {
    int wave = tid >> 6, lane = tid & 63;
    int nw = nblk * 4;
    for (int row = bid * 4 + wave; row < N_NODES; row += nw) {
        const uint4* base = (const uint4*)(bitmap + (size_t)row * WPR);
        uint4 w = base[lane];
        int c = __popc(w.x) + __popc(w.y) + __popc(w.z) + __popc(w.w);
        int dw = row >> 5;
        int diag = 0;
        if ((dw >> 2) == lane) {
            unsigned word = ((dw & 3) == 0) ? w.x : ((dw & 3) == 1) ? w.y : ((dw & 3) == 2) ? w.z : w.w;
            diag = (int)((word >> (row & 31)) & 1u);
        }
        unsigned long long db = __ballot(diag);
        int p = c;
#pragma unroll
        for (int off = 1; off < 64; off <<= 1) {
            int v = __shfl_up(p, off);
            if (lane >= off) p += v;
        }
        int total = __shfl(p, 63);
        unsigned short* lp = list + (size_t)row * LSTRIDE + (p - c);
        int k = 0;
        unsigned wsv[4] = {w.x, w.y, w.z, w.w};
#pragma unroll
        for (int q = 0; q < 4; q++) {
            unsigned ww = wsv[q];
            int bc = lane * 128 + q * 32;
            while (ww) {
                int b = __builtin_ctz(ww);
                ww &= ww - 1;
                lp[k++] = (unsigned short)(bc + b);
            }
        }
        int len = total + (db == 0ull ? 1 : 0);
        if (db == 0ull && lane == 0) list[(size_t)row * LSTRIDE + total] = (unsigned short)row;
        if (lane == 0) {
            lens[row] = len;
            dinv[row] = 1.0f / sqrtf((float)len + 1e-5f);
        }
    }
}

// out[i] = relu(dinv[i] * sum_j dinv[j] * g[j]); 2 row-teams of 128 threads per 256-block
__device__ __forceinline__ void phase_aggregate(const unsigned short* __restrict__ list,
                                                const int* __restrict__ lens,
                                                const float* __restrict__ dinv,
                                                const uint4* __restrict__ g4,
                                                float* __restrict__ out, int bid, int nblk, int tid) {
    __shared__ unsigned short snbr[2][LSTRIDE];
    __shared__ float sdj[2][LSTRIDE];
    __shared__ float part[2][4][DIM];
    int team = tid >> 7;
    int ttid = tid & 127;
    int gq = ttid >> 5, l = ttid & 31;
    int nteams = nblk * 2;
    for (int base = 0; base < N_NODES; base += nteams) {
        int row = base + bid * 2 + team;
        bool active = row < N_NODES;
        int len = 0;
        if (active) {
            unsigned short nb = list[(size_t)row * LSTRIDE + ttid];
            snbr[team][ttid] = nb;
            sdj[team][ttid] = dinv[nb & (N_NODES - 1)];  // mask keeps garbage slots in-range; unused
            len = lens[row];
        }
        __syncthreads();
        if (active) {
            float a0 = 0.f, a1 = 0.f, a2 = 0.f, a3 = 0.f, a4 = 0.f, a5 = 0.f, a6 = 0.f, a7 = 0.f;
            float b0 = 0.f, b1 = 0.f, b2 = 0.f, b3 = 0.f, b4 = 0.f, b5 = 0.f, b6 = 0.f, b7 = 0.f;
            int i = gq;
            for (; i + 4 < len; i += 8) {
                int n0 = snbr[team][i];
                int n1 = snbr[team][i + 4];
                float d0 = sdj[team][i];
                float d1 = sdj[team][i + 4];
                uint4 u0 = g4[(size_t)n0 * 32 + l];
                uint4 u1 = g4[(size_t)n1 * 32 + l];
                a0 = fmaf(d0, __uint_as_float(u0.x << 16), a0);
                a1 = fmaf(d0, __uint_as_float(u0.x & 0xffff0000u), a1);
                a2 = fmaf(d0, __uint_as_float(u0.y << 16), a2);
                a3 = fmaf(d0, __uint_as_float(u0.y & 0xffff0000u), a3);
                a4 = fmaf(d0, __uint_as_float(u0.z << 16), a4);
                a5 = fmaf(d0, __uint_as_float(u0.z & 0xffff0000u), a5);
                a6 = fmaf(d0, __uint_as_float(u0.w << 16), a6);
                a7 = fmaf(d0, __uint_as_float(u0.w & 0xffff0000u), a7);
                b0 = fmaf(d1, __uint_as_float(u1.x << 16), b0);
                b1 = fmaf(d1, __uint_as_float(u1.x & 0xffff0000u), b1);
                b2 = fmaf(d1, __uint_as_float(u1.y << 16), b2);
                b3 = fmaf(d1, __uint_as_float(u1.y & 0xffff0000u), b3);
                b4 = fmaf(d1, __uint_as_float(u1.z << 16), b4);
                b5 = fmaf(d1, __uint_as_float(u1.z & 0xffff0000u), b5);
                b6 = fmaf(d1, __uint_as_float(u1.w << 16), b6);
                b7 = fmaf(d1, __uint_as_float(u1.w & 0xffff0000u), b7);
            }
            if (i < len) {
                int n0 = snbr[team][i];
                float d0 = sdj[team][i];
                uint4 u0 = g4[(size_t)n0 * 32 + l];
                a0 = fmaf(d0, __uint_as_float(u0.x << 16), a0);
                a1 = fmaf(d0, __uint_as_float(u0.x & 0xffff0000u), a1);
                a2 = fmaf(d0, __uint_as_float(u0.y << 16), a2);
                a3 = fmaf(d0, __uint_as_float(u0.y & 0xffff0000u), a3);
                a4 = fmaf(d0, __uint_as_float(u0.z << 16), a4);
                a5 = fmaf(d0, __uint_as_float(u0.z & 0xffff0000u), a5);
                a6 = fmaf(d0, __uint_as_float(u0.w << 16), a6);
                a7 = fmaf(d0, __uint_as_float(u0.w & 0xffff0000u), a7);
            }
            float* pp = &part[team][gq][l * 8];
            pp[0] = a0 + b0; pp[1] = a1 + b1; pp[2] = a2 + b2; pp[3] = a3 + b3;
            pp[4] = a4 + b4; pp[5] = a5 + b5; pp[6] = a6 + b6; pp[7] = a7 + b7;
        }
        __syncthreads();
        if (active) {
            int f0 = ttid * 2;
            float s = dinv[row];
            float r0 = (part[team][0][f0] + part[team][1][f0]) + (part[team][2][f0] + part[team][3][f0]);
            float r1 = (part[team][0][f0 + 1] + part[team][1][f0 + 1]) + (part[team][2][f0 + 1] + part[team][3][f0 + 1]);
            float2 o;
            o.x = fmaxf(s * r0, 0.f);
            o.y = fmaxf(s * r1, 0.f);
            *(float2*)(out + (size_t)row * DIM + f0) = o;
        }
        __syncthreads();  // protect snbr/sdj/part before next iteration
    }
}

// ================= fused cooperative kernel =================
__global__ __launch_bounds__(256, 4) void fused_gcn(const float* __restrict__ x,
                                                    const int* __restrict__ ei,
                                                    const float* __restrict__ W,
                                                    float* __restrict__ out,
                                                    unsigned* __restrict__ bitmap,
                                                    float* __restrict__ dinv,
                                                    int* __restrict__ lens,
                                                    unsigned short* __restrict__ list,
                                                    __hip_bfloat16* __restrict__ xb,
                                                    __hip_bfloat16* __restrict__ Wb,
                                                    __hip_bfloat16* __restrict__ g,
                                                    int E) {
    cg::grid_group grid = cg::this_grid();
    int tid = threadIdx.x, bid = blockIdx.x, nblk = gridDim.x;
    int gtid = bid * 256 + tid, nth = nblk * 256;

    // P0: zero the dedup bitmap
    phase_zero(bitmap, gtid, nth);
    grid.sync();

    // P1: scatter edge atomics (latency-bound) overlapped with bf16 convert (BW-bound)
    phase_scatter(ei, ei + E, bitmap, E, gtid, nth);
    phase_convert(x, W, xb, Wb, gtid, nth);
    grid.sync();

    // P2: gemm (half the blocks) || dinv+list (other half) — independent
    int half = nblk >> 1;
    if (bid < half) phase_gemm((const short*)xb, (const short*)Wb, g, bid, half, tid);
    else            phase_dinvlist(bitmap, dinv, lens, list, bid - half, nblk - half, tid);
    grid.sync();

    // P3: gather-aggregate with per-neighbor dinv_j scaling
    phase_aggregate(list, lens, dinv, (const uint4*)g, out, bid, nblk, tid);
}

// ================= fallback standalone kernels (same phase bodies) =================
__global__ __launch_bounds__(256) void k_init(const float* __restrict__ x, const float* __restrict__ W,
                                              unsigned* __restrict__ bitmap,
                                              __hip_bfloat16* __restrict__ xb, __hip_bfloat16* __restrict__ Wb) {
    int gtid = blockIdx.x * 256 + threadIdx.x, nth = gridDim.x * 256;
    phase_zero(bitmap, gtid, nth);
    phase_convert(x, W, xb, Wb, gtid, nth);
}
__global__ __launch_bounds__(256) void k_scatter(const int* __restrict__ ei, unsigned* __restrict__ bitmap, int E) {
    int gtid = blockIdx.x * 256 + threadIdx.x, nth = gridDim.x * 256;
    phase_scatter(ei, ei + E, bitmap, E, gtid, nth);
}
__global__ __launch_bounds__(256) void k_dinvlist(const unsigned* __restrict__ bitmap, float* __restrict__ dinv,
                                                  int* __restrict__ lens, unsigned short* __restrict__ list) {
    phase_dinvlist(bitmap, dinv, lens, list, blockIdx.x, gridDim.x, threadIdx.x);
}
__global__ __launch_bounds__(256) void k_gemm(const short* __restrict__ xb, const short* __restrict__ Wb,
                                              __hip_bfloat16* __restrict__ g) {
    phase_gemm(xb, Wb, g, blockIdx.x, gridDim.x, threadIdx.x);
}
__global__ __launch_bounds__(256) void k_aggregate(const unsigned short* __restrict__ list, const int* __restrict__ lens,
                                                   const float* __restrict__ dinv, const uint4* __restrict__ g4,
                                                   float* __restrict__ out) {
    phase_aggregate(list, lens, dinv, g4, out, blockIdx.x, gridDim.x, threadIdx.x);
}

extern "C" void kernel_launch(void* const* d_in, const int* in_sizes, int n_in,
                              void* d_out, int out_size, void* d_ws, size_t ws_size,
                              hipStream_t stream) {
    const float* x = (const float*)d_in[0];
    const int* ei = (const int*)d_in[1];   // [2, E] flat: rows then cols
    const float* W = (const float*)d_in[2];
    float* out = (float*)d_out;
    int E = in_sizes[1] / 2;

    unsigned char* ws = (unsigned char*)d_ws;
    size_t off = 0;
    unsigned* bitmap = (unsigned*)(ws + off); off += (size_t)N_NODES * WPR * 4;               // 8 MB
    float* dinv = (float*)(ws + off);         off += (size_t)N_NODES * 4;                     // 32 KB
    int* lens = (int*)(ws + off);             off += (size_t)N_NODES * 4;                     // 32 KB
    unsigned short* list = (unsigned short*)(ws + off); off += (size_t)N_NODES * LSTRIDE * 2; // 2 MB
    __hip_bfloat16* xb = (__hip_bfloat16*)(ws + off); off += (size_t)N_NODES * DIM * 2;       // 4 MB
    __hip_bfloat16* Wb = (__hip_bfloat16*)(ws + off); off += (size_t)DIM * DIM * 2;           // 128 KB
    __hip_bfloat16* g = (__hip_bfloat16*)(ws + off);  off += (size_t)N_NODES * DIM * 2;       // 4 MB

    int nblk = 1024;  // 4 blocks/CU x 256 CUs (VGPR capped at 128 by __launch_bounds__(256,4))
    int maxPerCU = 0;
    if (hipOccupancyMaxActiveBlocksPerMultiprocessor(&maxPerCU, fused_gcn, 256, 0) == hipSuccess && maxPerCU >= 1) {
        int cap = maxPerCU * 256;
        if (cap < nblk) nblk = cap;
    }

    const uint4* g4c = (const uint4*)g;
    void* args[12] = {(void*)&x, (void*)&ei, (void*)&W, (void*)&out, (void*)&bitmap, (void*)&dinv,
                      (void*)&lens, (void*)&list, (void*)&xb, (void*)&Wb, (void*)&g, (void*)&E};
    hipError_t rc = hipLaunchCooperativeKernel(fused_gcn, dim3(nblk), dim3(256), args, 0, stream);
    if (rc != hipSuccess) {
        // fallback: same phases as separate dispatches
        k_init<<<2048, 256, 0, stream>>>(x, W, bitmap, xb, Wb);
        k_scatter<<<1024, 256, 0, stream>>>(ei, bitmap, E);
        k_dinvlist<<<2048, 256, 0, stream>>>(bitmap, dinv, lens, list);
        k_gemm<<<512, 256, 0, stream>>>((const short*)xb, (const short*)Wb, g);
        k_aggregate<<<4096, 256, 0, stream>>>(list, lens, dinv, g4c, out);
    }
}

// Round 3
// 103.202 us; speedup vs baseline: 3.8690x; 3.8690x over previous
//
#include <hip/hip_runtime.h>
#include <hip/hip_bf16.h>
#include <math.h>

#define N_NODES 8192
#define DIM 256
#define WPR 256      // LDS dedup bitmap words per row = 8192/32
#define LSTRIDE 128  // per-row list stride (ushort); raw degree ~Binom(262144,1/8192), mean 32, P(>128)~0

typedef __attribute__((ext_vector_type(8))) short bf16x8;
typedef __attribute__((ext_vector_type(4))) float f32x4;

// ================= k1: bf16 convert (blocks [0,1056)) || edge scatter (rest) =================
// convert: one 8-float chunk per thread, exact cover (270336 threads).
// scatter: append col to row's raw list via atomicAdd cursor (lens pre-zeroed by memset).
__global__ __launch_bounds__(256) void k1_convert_scatter(
        const float* __restrict__ x, const float* __restrict__ W, const int* __restrict__ ei,
        __hip_bfloat16* __restrict__ xb, __hip_bfloat16* __restrict__ Wb,
        unsigned short* __restrict__ list, int* __restrict__ lens, int E) {
    const int CONV_BLOCKS = (N_NODES * DIM / 8 + DIM * DIM / 8) / 256;  // 1056
    if ((int)blockIdx.x < CONV_BLOCKS) {
        int t = blockIdx.x * 256 + threadIdx.x;
        const int NX8 = N_NODES * DIM / 8;  // 262144
        const float* src = x;
        __hip_bfloat16* dst = xb;
        size_t off = (size_t)t * 8;
        if (t >= NX8) { src = W; dst = Wb; off = (size_t)(t - NX8) * 8; }
        float4 v0 = *(const float4*)(src + off);
        float4 v1 = *(const float4*)(src + off + 4);
        union { __hip_bfloat16 h[8]; uint4 u; } c;
        c.h[0] = __float2bfloat16(v0.x); c.h[1] = __float2bfloat16(v0.y);
        c.h[2] = __float2bfloat16(v0.z); c.h[3] = __float2bfloat16(v0.w);
        c.h[4] = __float2bfloat16(v1.x); c.h[5] = __float2bfloat16(v1.y);
        c.h[6] = __float2bfloat16(v1.z); c.h[7] = __float2bfloat16(v1.w);
        *(uint4*)(dst + off) = c.u;
    } else {
        int sid = (blockIdx.x - CONV_BLOCKS) * 256 + threadIdx.x;
        int snth = (gridDim.x - CONV_BLOCKS) * 256;
        const int* rows = ei;
        const int* cols = ei + E;
        for (int e = sid; e < E; e += snth) {
            int r = rows[e];
            int c = cols[e];
            int pos = atomicAdd(&lens[r], 1);
            if (pos < LSTRIDE) list[(size_t)r * LSTRIDE + pos] = (unsigned short)c;
        }
    }
}

// ================= k2: MFMA gemm (blocks [0,512)) || wave-local dedup+dinv (blocks [512,1024)) =================
// gemm: g = bf16(x @ W^T) UNSCALED (dinv applied in aggregate); one 64x64 tile per block.
// dedup: one wave per row; 1KB LDS bitmap; atomicOr-returns-old gives exactly-one-keep;
//        ballot prefix-sum compacts kept cols in place; append self-loop if absent.
__global__ __launch_bounds__(256) void k2_gemm_dedup(
        const short* __restrict__ xb, const short* __restrict__ Wb, __hip_bfloat16* __restrict__ g,
        unsigned short* __restrict__ list, int* __restrict__ lens, float* __restrict__ dinv) {
    __shared__ unsigned sbm[4][WPR];  // 4 KB; wave-private regions, no __syncthreads needed
    if ((int)blockIdx.x < 512) {
        int tid = threadIdx.x;
        int wave = tid >> 6, lane = tid & 63;
        int quad = lane >> 4, l16 = lane & 15;
        int t = blockIdx.x;
        int bm = (t & 127) * 64 + wave * 16;
        int bn = (t >> 7) * 64;
        f32x4 acc[4] = {};
        const short* arow = xb + (size_t)(bm + l16) * DIM + quad * 8;
#pragma unroll
        for (int k0 = 0; k0 < DIM; k0 += 32) {
            bf16x8 a = *(const bf16x8*)(arow + k0);
#pragma unroll
            for (int s = 0; s < 4; s++) {
                bf16x8 b = *(const bf16x8*)(Wb + (size_t)(bn + s * 16 + l16) * DIM + k0 + quad * 8);
                acc[s] = __builtin_amdgcn_mfma_f32_16x16x32_bf16(a, b, acc[s], 0, 0, 0);
            }
        }
        // C/D layout: col = lane&15 (n), row = quad*4 + r (m)
#pragma unroll
        for (int r = 0; r < 4; r++) {
            int m = bm + quad * 4 + r;
#pragma unroll
            for (int s = 0; s < 4; s++)
                g[(size_t)m * DIM + bn + s * 16 + l16] = __float2bfloat16(acc[s][r]);
        }
    } else {
        int bid = blockIdx.x - 512;
        int wave = threadIdx.x >> 6, lane = threadIdx.x & 63;
        for (int row = bid * 4 + wave; row < N_NODES; row += 512 * 4) {
            uint4 z = {0u, 0u, 0u, 0u};
            *(uint4*)&sbm[wave][lane * 4] = z;
            unsigned short* lp = list + (size_t)row * LSTRIDE;
            int raw = lens[row];
            if (raw > LSTRIDE) raw = LSTRIDE;
            // load both halves BEFORE any store (wave-wide vmcnt orders load->use->store)
            int c0 = (lane < raw) ? (int)lp[lane] : -1;
            int c1 = (64 + lane < raw) ? (int)lp[64 + lane] : -1;
            int new0 = 0, new1 = 0;
            if (c0 >= 0) {
                unsigned old = atomicOr(&sbm[wave][c0 >> 5], 1u << (c0 & 31));
                new0 = !((old >> (c0 & 31)) & 1u);
            }
            if (c1 >= 0) {
                unsigned old = atomicOr(&sbm[wave][c1 >> 5], 1u << (c1 & 31));
                new1 = !((old >> (c1 & 31)) & 1u);
            }
            unsigned long long m0 = __ballot(new0);
            unsigned long long m1 = __ballot(new1);
            unsigned long long below = (1ull << lane) - 1ull;  // lane 63: 0x7fff... correct
            int kept0 = __popcll(m0);
            int pos0 = __popcll(m0 & below);
            int pos1 = kept0 + __popcll(m1 & below);
            int total = kept0 + __popcll(m1);
            int diag = (int)((sbm[wave][row >> 5] >> (row & 31)) & 1u);  // LDS in-order per wave
            if (new0) lp[pos0] = (unsigned short)c0;
            if (new1) lp[pos1] = (unsigned short)c1;
            if (!diag && lane == 0) lp[total] = (unsigned short)row;
            if (lane == 0) {
                int len = total + (diag ? 0 : 1);
                lens[row] = len;
                dinv[row] = 1.0f / sqrtf((float)len + 1e-5f);
            }
        }
    }
}

// ================= k3: out[i] = relu(dinv_i * sum_j dinv_j * g[j]) =================
// one row per 128-thread block; 4 neighbor-groups x 32 lanes; 16B gathers; LDS cross-group reduce.
__global__ __launch_bounds__(128) void k3_aggregate(
        const unsigned short* __restrict__ list, const int* __restrict__ lens,
        const float* __restrict__ dinv, const uint4* __restrict__ g4, float* __restrict__ out) {
    __shared__ unsigned short snbr[LSTRIDE];
    __shared__ float sdj[LSTRIDE];
    __shared__ float part[4][DIM];
    int row = blockIdx.x;
    int tid = threadIdx.x;
    unsigned short nb = list[(size_t)row * LSTRIDE + tid];
    snbr[tid] = nb;
    sdj[tid] = dinv[nb & (N_NODES - 1)];  // mask: stale/poison slots stay in-range; unused
    int len = lens[row];
    __syncthreads();
    int gq = tid >> 5, l = tid & 31;
    float a0 = 0.f, a1 = 0.f, a2 = 0.f, a3 = 0.f, a4 = 0.f, a5 = 0.f, a6 = 0.f, a7 = 0.f;
    float b0 = 0.f, b1 = 0.f, b2 = 0.f, b3 = 0.f, b4 = 0.f, b5 = 0.f, b6 = 0.f, b7 = 0.f;
    int i = gq;
    for (; i + 4 < len; i += 8) {
        int n0 = snbr[i];
        int n1 = snbr[i + 4];
        float d0 = sdj[i];
        float d1 = sdj[i + 4];
        uint4 u0 = g4[(size_t)n0 * 32 + l];
        uint4 u1 = g4[(size_t)n1 * 32 + l];
        a0 = fmaf(d0, __uint_as_float(u0.x << 16), a0);
        a1 = fmaf(d0, __uint_as_float(u0.x & 0xffff0000u), a1);
        a2 = fmaf(d0, __uint_as_float(u0.y << 16), a2);
        a3 = fmaf(d0, __uint_as_float(u0.y & 0xffff0000u), a3);
        a4 = fmaf(d0, __uint_as_float(u0.z << 16), a4);
        a5 = fmaf(d0, __uint_as_float(u0.z & 0xffff0000u), a5);
        a6 = fmaf(d0, __uint_as_float(u0.w << 16), a6);
        a7 = fmaf(d0, __uint_as_float(u0.w & 0xffff0000u), a7);
        b0 = fmaf(d1, __uint_as_float(u1.x << 16), b0);
        b1 = fmaf(d1, __uint_as_float(u1.x & 0xffff0000u), b1);
        b2 = fmaf(d1, __uint_as_float(u1.y << 16), b2);
        b3 = fmaf(d1, __uint_as_float(u1.y & 0xffff0000u), b3);
        b4 = fmaf(d1, __uint_as_float(u1.z << 16), b4);
        b5 = fmaf(d1, __uint_as_float(u1.z & 0xffff0000u), b5);
        b6 = fmaf(d1, __uint_as_float(u1.w << 16), b6);
        b7 = fmaf(d1, __uint_as_float(u1.w & 0xffff0000u), b7);
    }
    if (i < len) {
        int n0 = snbr[i];
        float d0 = sdj[i];
        uint4 u0 = g4[(size_t)n0 * 32 + l];
        a0 = fmaf(d0, __uint_as_float(u0.x << 16), a0);
        a1 = fmaf(d0, __uint_as_float(u0.x & 0xffff0000u), a1);
        a2 = fmaf(d0, __uint_as_float(u0.y << 16), a2);
        a3 = fmaf(d0, __uint_as_float(u0.y & 0xffff0000u), a3);
        a4 = fmaf(d0, __uint_as_float(u0.z << 16), a4);
        a5 = fmaf(d0, __uint_as_float(u0.z & 0xffff0000u), a5);
        a6 = fmaf(d0, __uint_as_float(u0.w << 16), a6);
        a7 = fmaf(d0, __uint_as_float(u0.w & 0xffff0000u), a7);
    }
    float* pp = &part[gq][l * 8];
    pp[0] = a0 + b0; pp[1] = a1 + b1; pp[2] = a2 + b2; pp[3] = a3 + b3;
    pp[4] = a4 + b4; pp[5] = a5 + b5; pp[6] = a6 + b6; pp[7] = a7 + b7;
    __syncthreads();
    int f0 = tid * 2;
    float s = dinv[row];
    float r0 = (part[0][f0] + part[1][f0]) + (part[2][f0] + part[3][f0]);
    float r1 = (part[0][f0 + 1] + part[1][f0 + 1]) + (part[2][f0 + 1] + part[3][f0 + 1]);
    float2 o;
    o.x = fmaxf(s * r0, 0.f);
    o.y = fmaxf(s * r1, 0.f);
    *(float2*)(out + (size_t)row * DIM + f0) = o;
}

extern "C" void kernel_launch(void* const* d_in, const int* in_sizes, int n_in,
                              void* d_out, int out_size, void* d_ws, size_t ws_size,
                              hipStream_t stream) {
    const float* x = (const float*)d_in[0];
    const int* ei = (const int*)d_in[1];   // [2, E] flat: rows then cols
    const float* W = (const float*)d_in[2];
    float* out = (float*)d_out;
    int E = in_sizes[1] / 2;

    unsigned char* ws = (unsigned char*)d_ws;
    size_t off = 0;
    int* lens = (int*)(ws + off);                       off += (size_t)N_NODES * 4;            // 32 KB
    float* dinv = (float*)(ws + off);                   off += (size_t)N_NODES * 4;            // 32 KB
    unsigned short* list = (unsigned short*)(ws + off); off += (size_t)N_NODES * LSTRIDE * 2;  // 2 MB
    __hip_bfloat16* xb = (__hip_bfloat16*)(ws + off);   off += (size_t)N_NODES * DIM * 2;      // 4 MB
    __hip_bfloat16* Wb = (__hip_bfloat16*)(ws + off);   off += (size_t)DIM * DIM * 2;          // 128 KB
    __hip_bfloat16* g = (__hip_bfloat16*)(ws + off);    off += (size_t)N_NODES * DIM * 2;      // 4 MB

    hipMemsetAsync(lens, 0, (size_t)N_NODES * 4, stream);                // 32 KB fill
    const int CONV_BLOCKS = (N_NODES * DIM / 8 + DIM * DIM / 8) / 256;   // 1056
    k1_convert_scatter<<<CONV_BLOCKS + 512, 256, 0, stream>>>(x, W, ei, xb, Wb, list, lens, E);
    k2_gemm_dedup<<<1024, 256, 0, stream>>>((const short*)xb, (const short*)Wb, g, list, lens, dinv);
    k3_aggregate<<<N_NODES, 128, 0, stream>>>(list, lens, dinv, (const uint4*)g, out);
}